// Round 1
// baseline (3676.604 us; speedup 1.0000x reference)
//
#include <hip/hip_runtime.h>
#include <hip/hip_fp8.h>

// ---------------- common helpers ----------------
typedef short bf16x8 __attribute__((ext_vector_type(8)));
typedef float f32x4 __attribute__((ext_vector_type(4)));
typedef long long ll;

__device__ __forceinline__ unsigned short f2bf(float f) {
    union { float f; unsigned u; } v; v.f = f;
    unsigned u = v.u;
    unsigned r = (u + 0x7FFFu + ((u >> 16) & 1u)) >> 16;
    return (unsigned short)r;
}
__device__ __forceinline__ float bf2f(unsigned short h) {
    union { unsigned u; float f; } v; v.u = ((unsigned)h) << 16; return v.f;
}
__device__ __forceinline__ unsigned char f2fp8(float f) {
    __hip_fp8_e4m3 q(f);
    return (unsigned char)q.__x;
}

typedef const __attribute__((address_space(1))) void gas_void;
typedef __attribute__((address_space(3))) void las_void;
__device__ __forceinline__ void gll16(const void* g, void* l) {
    __builtin_amdgcn_global_load_lds((gas_void*)g, (las_void*)l, 16, 0, 0);
}

// counted-vmcnt + raw barrier (no compiler drain), sched-fenced (rule 18 / m201)
template<int N> __device__ __forceinline__ void wb() {
    __builtin_amdgcn_sched_barrier(0);
    if constexpr (N == 8)      asm volatile("s_waitcnt vmcnt(8)" ::: "memory");
    else if constexpr (N == 6) asm volatile("s_waitcnt vmcnt(6)" ::: "memory");
    else if constexpr (N == 4) asm volatile("s_waitcnt vmcnt(4)" ::: "memory");
    else if constexpr (N == 3) asm volatile("s_waitcnt vmcnt(3)" ::: "memory");
    else                       asm volatile("s_waitcnt vmcnt(0)" ::: "memory");
    __builtin_amdgcn_s_barrier();
    __builtin_amdgcn_sched_barrier(0);
}

// ---------------- deep-pipelined big-tile bf16 GEMM ----------------
// C[M,N] = alpha * A[M,K] @ Bt[N,K]^T ; ring-4 LDS, prefetch 3 tiles, counted vmcnt.
// BK=32. 8 waves (2M x 4N). Requires M%BM==0, N%BN==0, K%32==0, K>=128.
// LDS layout per tile buf: pair p=row>>1 owns 128B; chunk c(row,cc)=(((row&1)<<2)|cc)^(p&7)
// -> every ds_read_b128 fragment load spreads 64 lanes across all 32 banks.
template<int BM, int BN>
__global__ __launch_bounds__(512, 2) void gemm_big_k(
    const unsigned short* __restrict__ A, ll lda,
    const unsigned short* __restrict__ B, ll ldb,
    void* __restrict__ C, ll ldc,
    int K, float alpha, int mode, const float* __restrict__ res)
{
    constexpr int MI  = BM / 32;   // A fragments per wave
    constexpr int NI  = BN / 64;   // B fragments per wave
    constexpr int LPA = BM / 128;  // gll16 per thread for A tile
    constexpr int LPB = BN / 128;
    constexpr int LPT = LPA + LPB;
    __shared__ unsigned short sA[4 * BM * 32];
    __shared__ unsigned short sB[4 * BN * 32];

    // bijective XCD-aware block swizzle (m204)
    const int nwg = gridDim.x * gridDim.y;
    int id = blockIdx.y * gridDim.x + blockIdx.x;
    {
        int q = nwg >> 3, r = nwg & 7, x = id & 7, bb = id >> 3;
        id = (x < r ? x * (q + 1) : r * (q + 1) + (x - r) * q) + bb;
    }
    const int n0 = (id % gridDim.x) * BN;
    const int m0 = (id / gridDim.x) * BM;

    const unsigned short* Ab = A + (ll)m0 * lda;
    const unsigned short* Bb = B + (ll)n0 * ldb;

    const int t    = threadIdx.x;
    const int lane = t & 63;
    const int w    = t >> 6, wm = w >> 2, wn = w & 3;
    const int m16  = lane & 15, quad = lane >> 4;

    // staging: linear LDS dst (d = j*8192 + t*16 bytes), inverse-swizzled global src
    int srcA[LPA], srcB[LPB], dstA[LPA], dstB[LPB];
#pragma unroll
    for (int j = 0; j < LPA; j++) {
        int d = j * 8192 + t * 16;
        int p = d >> 7;
        int e = ((d >> 4) & 7) ^ (p & 7);
        int row = (p << 1) | (e >> 2);
        srcA[j] = row * (int)lda + (e & 3) * 8;
        dstA[j] = j * 4096 + t * 8;
    }
#pragma unroll
    for (int j = 0; j < LPB; j++) {
        int d = j * 8192 + t * 16;
        int p = d >> 7;
        int e = ((d >> 4) & 7) ^ (p & 7);
        int row = (p << 1) | (e >> 2);
        srcB[j] = row * (int)ldb + (e & 3) * 8;
        dstB[j] = j * 4096 + t * 8;
    }

    // fragment read offsets (elements) in swizzled layout
    int aoff[MI], boff[NI];
#pragma unroll
    for (int mi = 0; mi < MI; mi++) {
        int r = wm * (BM / 2) + mi * 16 + m16;
        int c = (((r & 1) << 2) | quad) ^ ((r >> 1) & 7);
        aoff[mi] = (r >> 1) * 64 + (c << 3);
    }
#pragma unroll
    for (int ni = 0; ni < NI; ni++) {
        int r = wn * 64 + ni * 16 + m16;
        int c = (((r & 1) << 2) | quad) ^ ((r >> 1) & 7);
        boff[ni] = (r >> 1) * 64 + (c << 3);
    }

    f32x4 acc[MI][NI];
#pragma unroll
    for (int i = 0; i < MI; i++)
#pragma unroll
        for (int j = 0; j < NI; j++) acc[i][j] = (f32x4){0.f, 0.f, 0.f, 0.f};

    auto stage = [&](int tile) {
        const int s  = tile & 3;
        const int kt = tile << 5;
#pragma unroll
        for (int j = 0; j < LPA; j++)
            gll16(Ab + srcA[j] + kt, sA + s * (BM * 32) + dstA[j]);
#pragma unroll
        for (int j = 0; j < LPB; j++)
            gll16(Bb + srcB[j] + kt, sB + s * (BN * 32) + dstB[j]);
    };

    const int nT = K >> 5;
    stage(0); stage(1); stage(2);
    wb<2 * LPT>();                       // tile 0 landed (2 tiles may stay in flight)

    for (int T = 0; T < nT; ++T) {
        if (T + 3 < nT) stage(T + 3);    // prefetch 3 ahead into slot (T+3)&3 (= (T-1)&3, free)
        const unsigned short* bufA = sA + (T & 3) * (BM * 32);
        const unsigned short* bufB = sB + (T & 3) * (BN * 32);
        bf16x8 af[MI], bg[NI];
#pragma unroll
        for (int ni = 0; ni < NI; ni++) bg[ni] = *(const bf16x8*)(bufB + boff[ni]);
#pragma unroll
        for (int mi = 0; mi < MI; mi++) af[mi] = *(const bf16x8*)(bufA + aoff[mi]);
        __builtin_amdgcn_s_setprio(1);
#pragma unroll
        for (int mi = 0; mi < MI; mi++)
#pragma unroll
            for (int ni = 0; ni < NI; ni++)
                acc[mi][ni] = __builtin_amdgcn_mfma_f32_16x16x32_bf16(
                    af[mi], bg[ni], acc[mi][ni], 0, 0, 0);
        __builtin_amdgcn_s_setprio(0);
        // boundary: ensure tile T+1 fully in LDS; allow younger tiles to stay in flight
        if (T + 4 <= nT)      wb<2 * LPT>();
        else if (T + 3 == nT) wb<LPT>();
        else if (T + 2 == nT) wb<0>();
        // T == nT-1: fall through to epilogue
    }

#pragma unroll
    for (int mi = 0; mi < MI; mi++) {
#pragma unroll
        for (int ni = 0; ni < NI; ni++) {
#pragma unroll
            for (int r4 = 0; r4 < 4; r4++) {
                int row = m0 + wm * (BM / 2) + mi * 16 + quad * 4 + r4;
                int col = n0 + wn * 64 + ni * 16 + m16;
                ll idx = (ll)row * ldc + col;
                float v = acc[mi][ni][r4] * alpha;
                if (mode == 0) {
                    ((float*)C)[idx] = res ? (v + res[idx]) : v;
                } else if (mode == 1) {
                    ((unsigned short*)C)[idx] = f2bf(v);
                } else {
                    ((unsigned char*)C)[idx] = (row == col) ? (unsigned char)0 : f2fp8(v);
                }
            }
        }
    }
}

// ---------------- generic bf16 MFMA GEMM (R2 K-loop: gll16 dbuf, 1 barrier) ----------------
// kept for attention scores (causal, z-batch) and PV (N=128)
__global__ __launch_bounds__(256) void gemm_bf16(
    const unsigned short* __restrict__ A, ll lda, ll sAz,
    const unsigned short* __restrict__ B, ll ldb, ll sBz,
    void* __restrict__ C, ll ldc, ll sCz,
    int M, int N, int K,
    float alpha, int mode, int causal,
    const float* __restrict__ res)
{
    __shared__ unsigned short sA[2][4096];
    __shared__ unsigned short sB[2][4096];
    const int n0 = blockIdx.x * 128;
    const int m0 = blockIdx.y * 128;
    if (causal && n0 > m0) return;
    const int z = blockIdx.z;

    const unsigned short* Ab = A + (ll)z * sAz + (ll)m0 * lda;
    const unsigned short* Bb = B + (ll)z * sBz + (ll)n0 * ldb;

    const int t    = threadIdx.x;
    const int lane = t & 63;
    const int w    = t >> 6, wm = w >> 1, wn = w & 1;
    const int m16  = lane & 15, quad = lane >> 4;

    const int r0 = t >> 2, cs = t & 3;
    const int r1 = r0 + 64;
    const int c0 = cs ^ ((r0 >> 1) & 3);
    const int c1 = cs ^ ((r1 >> 1) & 3);
    const ll a_off0 = (ll)r0 * lda + c0 * 8;
    const ll a_off1 = (ll)r1 * lda + c1 * 8;
    const ll b_off0 = (ll)r0 * ldb + c0 * 8;
    const ll b_off1 = (ll)r1 * ldb + c1 * 8;
    const int dst = t * 8;

    int aoff[4], boff[4];
#pragma unroll
    for (int mi = 0; mi < 4; mi++) {
        int rr = wm * 64 + mi * 16 + m16;
        aoff[mi] = rr * 32 + ((quad ^ ((rr >> 1) & 3)) << 3);
    }
#pragma unroll
    for (int ni = 0; ni < 4; ni++) {
        int rr = wn * 64 + ni * 16 + m16;
        boff[ni] = rr * 32 + ((quad ^ ((rr >> 1) & 3)) << 3);
    }

    f32x4 acc[4][4];
#pragma unroll
    for (int i = 0; i < 4; i++)
#pragma unroll
        for (int j = 0; j < 4; j++) acc[i][j] = (f32x4){0.f, 0.f, 0.f, 0.f};

    gll16(Ab + a_off0, sA[0] + dst);
    gll16(Ab + a_off1, sA[0] + 2048 + dst);
    gll16(Bb + b_off0, sB[0] + dst);
    gll16(Bb + b_off1, sB[0] + 2048 + dst);
    __syncthreads();

    for (int kt = 0; kt < K; kt += 32) {
        const int cur = (kt >> 5) & 1;
        if (kt + 32 < K) {
            const int nxt = cur ^ 1;
            gll16(Ab + a_off0 + kt + 32, sA[nxt] + dst);
            gll16(Ab + a_off1 + kt + 32, sA[nxt] + 2048 + dst);
            gll16(Bb + b_off0 + kt + 32, sB[nxt] + dst);
            gll16(Bb + b_off1 + kt + 32, sB[nxt] + 2048 + dst);
        }
        bf16x8 af[4], bg[4];
#pragma unroll
        for (int mi = 0; mi < 4; mi++) af[mi] = *(const bf16x8*)(sA[cur] + aoff[mi]);
#pragma unroll
        for (int ni = 0; ni < 4; ni++) bg[ni] = *(const bf16x8*)(sB[cur] + boff[ni]);
#pragma unroll
        for (int mi = 0; mi < 4; mi++)
#pragma unroll
            for (int ni = 0; ni < 4; ni++)
                acc[mi][ni] = __builtin_amdgcn_mfma_f32_16x16x32_bf16(
                    af[mi], bg[ni], acc[mi][ni], 0, 0, 0);
        __syncthreads();
    }

    const ll czoff = (ll)z * sCz;
#pragma unroll
    for (int mi = 0; mi < 4; mi++) {
#pragma unroll
        for (int ni = 0; ni < 4; ni++) {
#pragma unroll
            for (int r = 0; r < 4; r++) {
                int row = m0 + wm * 64 + mi * 16 + quad * 4 + r;
                int col = n0 + wn * 64 + ni * 16 + m16;
                ll idx = czoff + (ll)row * ldc + col;
                float v = acc[mi][ni][r] * alpha;
                if (mode == 0) {
                    ((float*)C)[idx] = res ? (v + res[idx]) : v;
                } else if (mode == 1) {
                    ((unsigned short*)C)[idx] = f2bf(v);
                } else {
                    ((unsigned char*)C)[idx] = (row == col) ? (unsigned char)0 : f2fp8(v);
                }
            }
        }
    }
}

// ---------------- fp8 MFMA GEMM for the LCA a@G chain ----------------
__global__ __launch_bounds__(256) void gemm_fp8(
    const unsigned char* __restrict__ A, ll lda,
    const unsigned char* __restrict__ B, ll ldb,
    int M, int N, int K, float alpha, int mode,
    unsigned short* __restrict__ uu, const unsigned short* __restrict__ cc,
    void* __restrict__ Out)
{
    __shared__ unsigned char sA[2][8192];
    __shared__ unsigned char sB[2][8192];
    const int n0 = blockIdx.x * 128;
    const int m0 = blockIdx.y * 128;

    const unsigned char* Ab = A + (ll)m0 * lda;
    const unsigned char* Bb = B + (ll)n0 * ldb;

    const int t    = threadIdx.x;
    const int lane = t & 63;
    const int w    = t >> 6, wm = w >> 1, wn = w & 1;
    const int m16  = lane & 15, quad = lane >> 4;

    const int r0 = t >> 2, cs = t & 3;
    const int r1 = r0 + 64;
    const int c0 = cs ^ ((r0 >> 1) & 3);
    const int c1 = cs ^ ((r1 >> 1) & 3);
    const ll a_off0 = (ll)r0 * lda + c0 * 16;
    const ll a_off1 = (ll)r1 * lda + c1 * 16;
    const ll b_off0 = (ll)r0 * ldb + c0 * 16;
    const ll b_off1 = (ll)r1 * ldb + c1 * 16;
    const int dst = t * 16;

    int aoff[4][2], boff[4][2];
#pragma unroll
    for (int mi = 0; mi < 4; mi++) {
        int rr = wm * 64 + mi * 16 + m16;
#pragma unroll
        for (int kh = 0; kh < 2; kh++) {
            int ch = kh * 2 + (quad >> 1);
            aoff[mi][kh] = rr * 64 + ((ch ^ ((rr >> 1) & 3)) << 4) + ((quad & 1) << 3);
        }
    }
#pragma unroll
    for (int ni = 0; ni < 4; ni++) {
        int rr = wn * 64 + ni * 16 + m16;
#pragma unroll
        for (int kh = 0; kh < 2; kh++) {
            int ch = kh * 2 + (quad >> 1);
            boff[ni][kh] = rr * 64 + ((ch ^ ((rr >> 1) & 3)) << 4) + ((quad & 1) << 3);
        }
    }

    f32x4 acc[4][4];
#pragma unroll
    for (int i = 0; i < 4; i++)
#pragma unroll
        for (int j = 0; j < 4; j++) acc[i][j] = (f32x4){0.f, 0.f, 0.f, 0.f};

    gll16(Ab + a_off0, sA[0] + dst);
    gll16(Ab + a_off1, sA[0] + 4096 + dst);
    gll16(Bb + b_off0, sB[0] + dst);
    gll16(Bb + b_off1, sB[0] + 4096 + dst);
    __syncthreads();

    for (int kt = 0; kt < K; kt += 64) {
        const int cur = (kt >> 6) & 1;
        if (kt + 64 < K) {
            const int nxt = cur ^ 1;
            gll16(Ab + a_off0 + kt + 64, sA[nxt] + dst);
            gll16(Ab + a_off1 + kt + 64, sA[nxt] + 4096 + dst);
            gll16(Bb + b_off0 + kt + 64, sB[nxt] + dst);
            gll16(Bb + b_off1 + kt + 64, sB[nxt] + 4096 + dst);
        }
#pragma unroll
        for (int kh = 0; kh < 2; kh++) {
            long long af[4], bg[4];
#pragma unroll
            for (int mi = 0; mi < 4; mi++)
                af[mi] = *(const long long*)(sA[cur] + aoff[mi][kh]);
#pragma unroll
            for (int ni = 0; ni < 4; ni++)
                bg[ni] = *(const long long*)(sB[cur] + boff[ni][kh]);
#pragma unroll
            for (int mi = 0; mi < 4; mi++)
#pragma unroll
                for (int ni = 0; ni < 4; ni++)
                    acc[mi][ni] = __builtin_amdgcn_mfma_f32_16x16x32_fp8_fp8(
                        af[mi], bg[ni], acc[mi][ni], 0, 0, 0);
        }
        __syncthreads();
    }

#pragma unroll
    for (int mi = 0; mi < 4; mi++) {
#pragma unroll
        for (int ni = 0; ni < 4; ni++) {
#pragma unroll
            for (int r = 0; r < 4; r++) {
                int row = m0 + wm * 64 + mi * 16 + quad * 4 + r;
                int col = n0 + wn * 64 + ni * 16 + m16;
                ll idx = (ll)row * N + col;
                float v = acc[mi][ni][r] * alpha;
                float un = 0.9f * bf2f(uu[idx]) + bf2f(cc[idx]) - v;
                uu[idx] = f2bf(un);
                float a = fmaxf(un - 0.1f, 0.0f);
                if (mode == 3) ((unsigned char*)Out)[idx] = f2fp8(a * 8.0f);
                else           ((unsigned short*)Out)[idx] = f2bf(a);
            }
        }
    }
}

// ---------------- elementwise / transform kernels ----------------

__global__ void wtrans_k(const float* __restrict__ in, unsigned short* __restrict__ out,
                         int R, int C) {
    __shared__ float tile[32][33];
    ll bx = (ll)blockIdx.x * 32, by = (ll)blockIdx.y * 32;
    int tx = threadIdx.x & 31, ty = threadIdx.x >> 5;
#pragma unroll
    for (int i = ty; i < 32; i += 8) tile[i][tx] = in[(by + i) * C + bx + tx];
    __syncthreads();
#pragma unroll
    for (int i = ty; i < 32; i += 8) out[(bx + i) * R + by + tx] = f2bf(tile[tx][i]);
}

__global__ void conv4_k(const float* __restrict__ in, unsigned short* __restrict__ out, ll n) {
    ll i = ((ll)blockIdx.x * 256 + threadIdx.x) * 4;
    if (i >= n) return;
    float4 v = *(const float4*)(in + i);
    out[i] = f2bf(v.x); out[i + 1] = f2bf(v.y); out[i + 2] = f2bf(v.z); out[i + 3] = f2bf(v.w);
}

__global__ void rmsnorm_k(const float* __restrict__ in, const float* __restrict__ w,
                          unsigned short* __restrict__ out) {
    int row = blockIdx.x, t = threadIdx.x;
    const float* x = in + (ll)row * 2048;
    float v[8]; float s = 0.f;
#pragma unroll
    for (int i = 0; i < 8; i++) { v[i] = x[t + i * 256]; s += v[i] * v[i]; }
#pragma unroll
    for (int o = 32; o > 0; o >>= 1) s += __shfl_xor(s, o, 64);
    __shared__ float rs[4];
    if ((t & 63) == 0) rs[t >> 6] = s;
    __syncthreads();
    s = (rs[0] + rs[1] + rs[2] + rs[3]) * (1.0f / 2048.0f);
    float sc = rsqrtf(s + 1e-6f);
    unsigned short* o_ = out + (ll)row * 2048;
#pragma unroll
    for (int i = 0; i < 8; i++) o_[t + i * 256] = f2bf(v[i] * sc * w[t + i * 256]);
}

__global__ void rope_k(unsigned short* __restrict__ q, unsigned short* __restrict__ k) {
    int idx = blockIdx.x * 256 + threadIdx.x;
    int j = idx & 63;
    int h = (idx >> 6) & 15;
    int row = idx >> 10;
    int s = row & 2047;
    float f = __expf(-(float)j * 0.14391156831212783f);
    float ang = (float)s * f;
    float sn, cs;
    sincosf(ang, &sn, &cs);
    ll base = (ll)row * 2048 + h * 128 + j;
    float x1 = bf2f(q[base]), x2 = bf2f(q[base + 64]);
    q[base]      = f2bf(x1 * cs - x2 * sn);
    q[base + 64] = f2bf(x2 * cs + x1 * sn);
    x1 = bf2f(k[base]); x2 = bf2f(k[base + 64]);
    k[base]      = f2bf(x1 * cs - x2 * sn);
    k[base + 64] = f2bf(x2 * cs + x1 * sn);
}

__global__ void vtrans_k(const unsigned short* __restrict__ in, unsigned short* __restrict__ out) {
    __shared__ unsigned short tile[32][33];
    int z = blockIdx.z, b = z >> 4, h = z & 15;
    const unsigned short* ib = in + (ll)b * 4194304 + h * 128;
    unsigned short* ob = out + (ll)z * 262144;
    int bx = blockIdx.x * 32, by = blockIdx.y * 32;
    int tx = threadIdx.x & 31, ty = threadIdx.x >> 5;
#pragma unroll
    for (int i = ty; i < 32; i += 8) tile[i][tx] = ib[(ll)(by + i) * 2048 + bx + tx];
    __syncthreads();
#pragma unroll
    for (int i = ty; i < 32; i += 8) ob[(ll)(bx + i) * 2048 + by + tx] = tile[tx][i];
}

__global__ void softmax_k(unsigned short* __restrict__ sc) {
    int q = blockIdx.x, z = blockIdx.y, t = threadIdx.x;
    unsigned short* row = sc + (ll)z * 4194304 + (ll)q * 2048;
    float x[8]; float m = -1e30f;
#pragma unroll
    for (int i = 0; i < 8; i++) {
        int kk = t + i * 256;
        x[i] = (kk <= q) ? bf2f(row[kk]) : -1e30f;
        m = fmaxf(m, x[i]);
    }
#pragma unroll
    for (int o = 32; o > 0; o >>= 1) m = fmaxf(m, __shfl_xor(m, o, 64));
    __shared__ float rm[4];
    if ((t & 63) == 0) rm[t >> 6] = m;
    __syncthreads();
    m = fmaxf(fmaxf(rm[0], rm[1]), fmaxf(rm[2], rm[3]));
    float s = 0.f;
#pragma unroll
    for (int i = 0; i < 8; i++) {
        int kk = t + i * 256;
        float e = (kk <= q) ? __expf(x[i] - m) : 0.0f;
        x[i] = e; s += e;
    }
#pragma unroll
    for (int o = 32; o > 0; o >>= 1) s += __shfl_xor(s, o, 64);
    __shared__ float rsum[4];
    if ((t & 63) == 0) rsum[t >> 6] = s;
    __syncthreads();
    s = rsum[0] + rsum[1] + rsum[2] + rsum[3];
    float inv = 1.0f / s;
#pragma unroll
    for (int i = 0; i < 8; i++) row[t + i * 256] = f2bf(x[i] * inv);
}

__global__ void lca_init_k(const unsigned short* __restrict__ c, unsigned short* __restrict__ u,
                           unsigned char* __restrict__ a) {
    ll i = ((ll)blockIdx.x * 256 + threadIdx.x) * 4;
#pragma unroll
    for (int j = 0; j < 4; j++) {
        unsigned short cv = c[i + j];
        u[i + j] = cv;
        a[i + j] = f2fp8(fmaxf(bf2f(cv) - 0.1f, 0.f) * 8.0f);
    }
}

__global__ void swiglu_k(unsigned short* __restrict__ g, const unsigned short* __restrict__ u) {
    ll i = ((ll)blockIdx.x * 256 + threadIdx.x) * 4;
#pragma unroll
    for (int j = 0; j < 4; j++) {
        float x = bf2f(g[i + j]);
        float y = bf2f(u[i + j]);
        float sil = x / (1.0f + __expf(-x));
        g[i + j] = f2bf(sil * y);
    }
}

// ---------------- host orchestration ----------------
extern "C" void kernel_launch(void* const* d_in, const int* in_sizes, int n_in,
                              void* d_out, int out_size, void* d_ws, size_t ws_size,
                              hipStream_t stream) {
    (void)in_sizes; (void)n_in; (void)out_size; (void)ws_size;
    const float* X        = (const float*)d_in[0];
    const float* wln_in   = (const float*)d_in[1];
    const float* wln_lca  = (const float*)d_in[2];
    const float* wln_post = (const float*)d_in[3];
    const float* Wq   = (const float*)d_in[4];
    const float* Wk   = (const float*)d_in[5];
    const float* Wv   = (const float*)d_in[6];
    const float* Wo   = (const float*)d_in[7];
    const float* Wlca = (const float*)d_in[8];
    const float* Wg   = (const float*)d_in[9];
    const float* Wu   = (const float*)d_in[10];
    const float* Wd   = (const float*)d_in[11];
    float* out = (float*)d_out;

    char* ws = (char*)d_ws;
    unsigned short* WqT = (unsigned short*)(ws);
    unsigned short* WkT = WqT + 4194304;
    unsigned short* WvT = WqT + 2 * 4194304;
    unsigned short* WoT = WqT + 3 * 4194304;
    unsigned short* WgT = WqT;
    unsigned short* WlcaT = (unsigned short*)(ws + 33554432);
    unsigned short* Wlcab = WlcaT + 8388608;
    unsigned short* WuT   = WlcaT;
    unsigned short* h_bf = (unsigned short*)(ws + 67108864);
    char* pool = ws + 83886080;
    // attention phase
    unsigned short* qb     = (unsigned short*)(pool);
    unsigned short* kb     = (unsigned short*)(pool + 16777216);
    unsigned short* vb     = (unsigned short*)(pool + 33554432);
    unsigned short* VT     = (unsigned short*)(pool + 50331648);
    unsigned short* attn   = (unsigned short*)(pool + 67108864);
    unsigned short* scores = (unsigned short*)(pool + 83886080);
    float* h1              = (float*)(pool + 150994944);
    // LCA phase
    unsigned short* cbuf   = (unsigned short*)(pool);
    unsigned short* ubuf   = (unsigned short*)(pool + 33554432);
    unsigned char* a8_0    = (unsigned char*)(pool + 67108864);
    unsigned char* a8_1    = (unsigned char*)(pool + 83886080);
    unsigned short* abf    = (unsigned short*)(pool + 100663296);
    unsigned char* Gf8     = (unsigned char*)(pool + 134217728);
    float* h2              = (float*)(pool + 150994944);
    // MLP phase
    unsigned short* gate   = (unsigned short*)(pool);
    unsigned short* up     = (unsigned short*)(pool + 67108864);
    unsigned short* WdT    = (unsigned short*)(pool + 201326592);

    dim3 blk(256);
    auto gemm = [&](const unsigned short* A, ll lda, ll sAz,
                    const unsigned short* Bt, ll ldb, ll sBz,
                    void* C, ll ldc, ll sCz,
                    int M, int N, int K, int Z,
                    float alpha, int mode, int causal, const float* res) {
        dim3 g(N / 128, M / 128, Z);
        gemm_bf16<<<g, blk, 0, stream>>>(A, lda, sAz, Bt, ldb, sBz, C, ldc, sCz,
                                         M, N, K, alpha, mode, causal, res);
    };
    auto gemm_big = [&](const unsigned short* A, ll lda, const unsigned short* Bt, ll ldb,
                        void* C, ll ldc, int M, int N, int K, float alpha, int mode,
                        const float* res, int wide) {
        if (wide) {
            dim3 g(N / 256, M / 256);
            gemm_big_k<256, 256><<<g, dim3(512), 0, stream>>>(A, lda, Bt, ldb, C, ldc,
                                                              K, alpha, mode, res);
        } else {
            dim3 g(N / 256, M / 128);
            gemm_big_k<128, 256><<<g, dim3(512), 0, stream>>>(A, lda, Bt, ldb, C, ldc,
                                                              K, alpha, mode, res);
        }
    };

    // --- weight prep ---
    wtrans_k<<<dim3(64, 64), blk, 0, stream>>>(Wq, WqT, 2048, 2048);
    wtrans_k<<<dim3(64, 64), blk, 0, stream>>>(Wk, WkT, 2048, 2048);
    wtrans_k<<<dim3(64, 64), blk, 0, stream>>>(Wv, WvT, 2048, 2048);
    wtrans_k<<<dim3(64, 64), blk, 0, stream>>>(Wo, WoT, 2048, 2048);
    wtrans_k<<<dim3(128, 64), blk, 0, stream>>>(Wlca, WlcaT, 2048, 4096);
    conv4_k<<<8192, blk, 0, stream>>>(Wlca, Wlcab, 8388608LL);

    // --- attention ---
    rmsnorm_k<<<4096, blk, 0, stream>>>(X, wln_in, h_bf);
    gemm_big(h_bf, 2048, WqT, 2048, qb, 2048, 4096, 2048, 2048, 1.f, 1, nullptr, 0);
    gemm_big(h_bf, 2048, WkT, 2048, kb, 2048, 4096, 2048, 2048, 1.f, 1, nullptr, 0);
    gemm_big(h_bf, 2048, WvT, 2048, vb, 2048, 4096, 2048, 2048, 1.f, 1, nullptr, 0);
    rope_k<<<16384, blk, 0, stream>>>(qb, kb);
    vtrans_k<<<dim3(4, 64, 32), blk, 0, stream>>>(vb, VT);
    for (int c = 0; c < 4; c++) {
        int b = c >> 1, h0 = (c & 1) * 8;
        const unsigned short* qbase = qb + (ll)b * 4194304 + h0 * 128;
        const unsigned short* kbase = kb + (ll)b * 4194304 + h0 * 128;
        gemm(qbase, 2048, 128, kbase, 2048, 128, scores, 2048, 4194304LL,
             2048, 2048, 128, 8, 0.08838834764831845f, 1, 1, nullptr);
        softmax_k<<<dim3(2048, 8), blk, 0, stream>>>(scores);
        const unsigned short* vtb = VT + (ll)(b * 16 + h0) * 262144;
        unsigned short* ab = attn + (ll)b * 4194304 + h0 * 128;
        gemm(scores, 2048, 4194304LL, vtb, 2048, 262144LL, ab, 2048, 128,
             2048, 128, 2048, 8, 1.f, 1, 0, nullptr);
    }
    gemm_big(attn, 2048, WoT, 2048, h1, 2048, 4096, 2048, 2048, 1.f, 0, X, 0);

    // --- LCA ---
    rmsnorm_k<<<4096, blk, 0, stream>>>(h1, wln_lca, h_bf);
    gemm_big(WlcaT, 2048, WlcaT, 2048, Gf8, 4096, 4096, 4096, 2048, 16.f, 2, nullptr, 1);
    gemm_big(h_bf, 2048, WlcaT, 2048, cbuf, 4096, 4096, 4096, 2048, 0.1f, 1, nullptr, 1);
    lca_init_k<<<16384, blk, 0, stream>>>(cbuf, ubuf, a8_0);
    unsigned char* acur = a8_0; unsigned char* anext = a8_1;
    for (int i = 0; i < 9; i++) {
        int mode = (i < 8) ? 3 : 4;
        void* outp = (i < 8) ? (void*)anext : (void*)abf;
        gemm_fp8<<<dim3(32, 32), blk, 0, stream>>>(
            acur, 4096, Gf8, 4096, 4096, 4096, 4096,
            0.1f / 128.0f, mode, ubuf, cbuf, outp);
        unsigned char* tmp = acur; acur = anext; anext = tmp;
    }
    gemm_big(abf, 4096, Wlcab, 4096, h2, 2048, 4096, 2048, 4096, 1.f, 0, nullptr, 0);

    // --- MLP ---
    wtrans_k<<<dim3(256, 64), blk, 0, stream>>>(Wg, WgT, 2048, 8192);
    wtrans_k<<<dim3(256, 64), blk, 0, stream>>>(Wu, WuT, 2048, 8192);
    wtrans_k<<<dim3(64, 256), blk, 0, stream>>>(Wd, WdT, 8192, 2048);
    rmsnorm_k<<<4096, blk, 0, stream>>>(h2, wln_post, h_bf);
    gemm_big(h_bf, 2048, WgT, 2048, gate, 8192, 4096, 8192, 2048, 1.f, 1, nullptr, 1);
    gemm_big(h_bf, 2048, WuT, 2048, up, 8192, 4096, 8192, 2048, 1.f, 1, nullptr, 1);
    swiglu_k<<<32768, blk, 0, stream>>>(gate, up);
    gemm_big(gate, 8192, WdT, 8192, out, 2048, 4096, 2048, 8192, 1.f, 0, h2, 0);
}

// Round 2
// 3285.709 us; speedup vs baseline: 1.1190x; 1.1190x over previous
//
#include <hip/hip_runtime.h>
#include <hip/hip_fp8.h>

// ---------------- common helpers ----------------
typedef short bf16x8 __attribute__((ext_vector_type(8)));
typedef float f32x4 __attribute__((ext_vector_type(4)));
typedef long long ll;

__device__ __forceinline__ unsigned short f2bf(float f) {
    union { float f; unsigned u; } v; v.f = f;
    unsigned u = v.u;
    unsigned r = (u + 0x7FFFu + ((u >> 16) & 1u)) >> 16;
    return (unsigned short)r;
}
__device__ __forceinline__ float bf2f(unsigned short h) {
    union { unsigned u; float f; } v; v.u = ((unsigned)h) << 16; return v.f;
}
__device__ __forceinline__ unsigned char f2fp8(float f) {
    __hip_fp8_e4m3 q(f);
    return (unsigned char)q.__x;
}

typedef const __attribute__((address_space(1))) void gas_void;
typedef __attribute__((address_space(3))) void las_void;
__device__ __forceinline__ void gll16(const void* g, void* l) {
    __builtin_amdgcn_global_load_lds((gas_void*)g, (las_void*)l, 16, 0, 0);
}

#define BAR __builtin_amdgcn_s_barrier()
#define LGKM0 do { asm volatile("s_waitcnt lgkmcnt(0)" ::: "memory"); __builtin_amdgcn_sched_barrier(0); } while (0)
#define VMC(n) asm volatile("s_waitcnt vmcnt(" #n ")" ::: "memory")

// ============ 8-phase 256x256 bf16 GEMM (m201 schedule port) ============
// C[M,N] = alpha * A[M,K] @ Bt[N,K]^T.  BK=64, 2 LDS buffers, 128-row half-regions.
// 8 waves (2M x 4N), per-wave 128x64 output.  K % 128 == 0, K >= 256.
// LDS swizzle: row r, 16B-chunk c stored at chunk c ^ (r&7)  (full 32-bank spread).
__global__ __launch_bounds__(512, 2) void gemm256_k(
    const unsigned short* __restrict__ A, ll lda,
    const unsigned short* __restrict__ B, ll ldb,
    void* __restrict__ C, ll ldc,
    int K, float alpha, int mode, const float* __restrict__ res)
{
    __shared__ unsigned short sA[2][2][8192];   // [slot][half(128 rows)][128*64]
    __shared__ unsigned short sB[2][2][8192];

    const int nwg = gridDim.x * gridDim.y;
    int id = blockIdx.y * gridDim.x + blockIdx.x;
    { int q = nwg >> 3, r = nwg & 7, x = id & 7, bb = id >> 3;
      id = (x < r ? x * (q + 1) : r * (q + 1) + (x - r) * q) + bb; }
    const int n0 = (id % gridDim.x) * 256;
    const int m0 = (id / gridDim.x) * 256;

    const unsigned short* Ab = A + (ll)m0 * lda;
    const unsigned short* Bb = B + (ll)n0 * ldb;

    const int t = threadIdx.x;
    const int lane = t & 63;
    const int w = t >> 6, wm = w >> 2, wn = w & 3;
    const int m16 = lane & 15, quad = lane >> 4;

    // staging: linear LDS dst, inverse-swizzled global src
    const int tr = t >> 3;                       // row within 64-row sweep
    const int tc8 = ((t & 7) ^ (tr & 7)) << 3;   // element col (swizzle involution)

    // fragment read offsets (elements); r&7 == m16&7 for all frags
    const int pk0 = m16 * 64 + (((quad    ) ^ (m16 & 7)) << 3);
    const int pk1 = m16 * 64 + (((4 + quad) ^ (m16 & 7)) << 3);

    auto stA = [&](int tile, int h) {
        char* d0 = (char*)&sA[tile & 1][h][0] + t * 16;
        const unsigned short* s0 = Ab + (ll)(h * 128 + tr) * lda + tc8 + (ll)tile * 64;
        gll16(s0, d0);
        gll16(s0 + 64 * lda, d0 + 8192);
    };
    auto stB = [&](int tile, int h) {
        char* d0 = (char*)&sB[tile & 1][h][0] + t * 16;
        const unsigned short* s0 = Bb + (ll)(h * 128 + tr) * ldb + tc8 + (ll)tile * 64;
        gll16(s0, d0);
        gll16(s0 + 64 * ldb, d0 + 8192);
    };
    auto ldA = [&](int s, int g, bf16x8 (&af)[4][2]) {
        const unsigned short* p0 = &sA[s][wm][g * 4096];
#pragma unroll
        for (int a2 = 0; a2 < 4; a2++) {
            af[a2][0] = *(const bf16x8*)(p0 + a2 * 1024 + pk0);
            af[a2][1] = *(const bf16x8*)(p0 + a2 * 1024 + pk1);
        }
    };
    auto ldB = [&](int s, int g, bf16x8 (&bg)[2][2]) {
        const unsigned short* p0 = &sB[s][wn >> 1][(wn & 1) * 4096 + g * 2048];
#pragma unroll
        for (int b2 = 0; b2 < 2; b2++) {
            bg[b2][0] = *(const bf16x8*)(p0 + b2 * 1024 + pk0);
            bg[b2][1] = *(const bf16x8*)(p0 + b2 * 1024 + pk1);
        }
    };

    f32x4 acc[8][4];
#pragma unroll
    for (int i = 0; i < 8; i++)
#pragma unroll
        for (int j = 0; j < 4; j++) acc[i][j] = (f32x4){0.f, 0.f, 0.f, 0.f};

    bf16x8 afA[4][2], afB[4][2], bgA[2][2], bgB[2][2];

#define MM256(af, bg, gm, gn) do { \
    __builtin_amdgcn_s_setprio(1); \
    _Pragma("unroll") \
    for (int a2 = 0; a2 < 4; a2++) \
    _Pragma("unroll") \
    for (int b2 = 0; b2 < 2; b2++) { \
        acc[(gm)*4+a2][(gn)*2+b2] = __builtin_amdgcn_mfma_f32_16x16x32_bf16(af[a2][0], bg[b2][0], acc[(gm)*4+a2][(gn)*2+b2], 0, 0, 0); \
        acc[(gm)*4+a2][(gn)*2+b2] = __builtin_amdgcn_mfma_f32_16x16x32_bf16(af[a2][1], bg[b2][1], acc[(gm)*4+a2][(gn)*2+b2], 0, 0, 0); \
    } \
    __builtin_amdgcn_s_setprio(0); \
} while (0)

    // prologue: tile0 fully + tile1 B halves (FIFO: B0,B1,A0,A1 per tile)
    stB(0, 0); stB(0, 1); stA(0, 0); stA(0, 1); stB(1, 0); stB(1, 1);
    VMC(4); BAR;

#define ITER256(T, LAST) do { \
    /* p1: tile T quadrant (mi0-3 x ni0-1) */ \
    stA((T) + 1, 0); \
    ldA(0, 0, afA); ldB(0, 0, bgA); \
    BAR; LGKM0; \
    MM256(afA, bgA, 0, 0); \
    BAR; \
    /* p2 */ \
    stA((T) + 1, 1); \
    ldB(0, 1, bgB); \
    BAR; LGKM0; \
    MM256(afA, bgB, 0, 1); \
    BAR; \
    /* p3 */ \
    if (!(LAST)) stB((T) + 2, 0); \
    ldA(0, 1, afB); \
    BAR; LGKM0; \
    MM256(afB, bgA, 1, 0); \
    BAR; \
    /* p4 */ \
    if (!(LAST)) stB((T) + 2, 1); \
    MM256(afB, bgB, 1, 1); \
    if (LAST) { VMC(0); } else { VMC(4); } \
    BAR; \
    /* p5: tile T+1 */ \
    if (!(LAST)) stA((T) + 2, 0); \
    ldA(1, 0, afA); ldB(1, 0, bgA); \
    BAR; LGKM0; \
    MM256(afA, bgA, 0, 0); \
    BAR; \
    /* p6 */ \
    if (!(LAST)) stA((T) + 2, 1); \
    ldB(1, 1, bgB); \
    BAR; LGKM0; \
    MM256(afA, bgB, 0, 1); \
    BAR; \
    /* p7 */ \
    if (!(LAST)) stB((T) + 3, 0); \
    ldA(1, 1, afB); \
    BAR; LGKM0; \
    MM256(afB, bgA, 1, 0); \
    BAR; \
    /* p8 */ \
    if (!(LAST)) stB((T) + 3, 1); \
    MM256(afB, bgB, 1, 1); \
    if (!(LAST)) { VMC(4); BAR; } \
} while (0)

    const int nIter = K >> 7;
    for (int i = 0; i < nIter - 1; ++i) ITER256(2 * i, false);
    ITER256(2 * (nIter - 1), true);

#pragma unroll
    for (int mi = 0; mi < 8; mi++) {
#pragma unroll
        for (int ni = 0; ni < 4; ni++) {
#pragma unroll
            for (int r4 = 0; r4 < 4; r4++) {
                int row = m0 + wm * 128 + mi * 16 + quad * 4 + r4;
                int col = n0 + wn * 64 + ni * 16 + m16;
                ll idx = (ll)row * ldc + col;
                float v = acc[mi][ni][r4] * alpha;
                if (mode == 0) ((float*)C)[idx] = res ? (v + res[idx]) : v;
                else if (mode == 1) ((unsigned short*)C)[idx] = f2bf(v);
                else ((unsigned char*)C)[idx] = (row == col) ? (unsigned char)0 : f2fp8(v);
            }
        }
    }
}

// ============ 8-phase-style 128x256 bf16 GEMM, 3-slot ring ============
// 8 waves 2M x 4N, per-wave 64x64.  2 phases per K-tile (BK=64).  K%64==0, K>=256.
__global__ __launch_bounds__(512, 2) void gemm128_k(
    const unsigned short* __restrict__ A, ll lda,
    const unsigned short* __restrict__ B, ll ldb,
    void* __restrict__ C, ll ldc,
    int K, float alpha, int mode, const float* __restrict__ res)
{
    __shared__ unsigned short sA[3][8192];      // [slot][128 rows * 64]
    __shared__ unsigned short sB[3][2][8192];   // [slot][half][128 rows * 64]

    const int nwg = gridDim.x * gridDim.y;
    int id = blockIdx.y * gridDim.x + blockIdx.x;
    { int q = nwg >> 3, r = nwg & 7, x = id & 7, bb = id >> 3;
      id = (x < r ? x * (q + 1) : r * (q + 1) + (x - r) * q) + bb; }
    const int n0 = (id % gridDim.x) * 256;
    const int m0 = (id / gridDim.x) * 128;

    const unsigned short* Ab = A + (ll)m0 * lda;
    const unsigned short* Bb = B + (ll)n0 * ldb;

    const int t = threadIdx.x;
    const int lane = t & 63;
    const int w = t >> 6, wm = w >> 2, wn = w & 3;
    const int m16 = lane & 15, quad = lane >> 4;

    const int tr = t >> 3;
    const int tc8 = ((t & 7) ^ (tr & 7)) << 3;
    const int pk0 = m16 * 64 + (((quad    ) ^ (m16 & 7)) << 3);
    const int pk1 = m16 * 64 + (((4 + quad) ^ (m16 & 7)) << 3);

    auto stA = [&](int tile, int s) {
        char* d0 = (char*)&sA[s][0] + t * 16;
        const unsigned short* s0 = Ab + (ll)tr * lda + tc8 + (ll)tile * 64;
        gll16(s0, d0);
        gll16(s0 + 64 * lda, d0 + 8192);
    };
    auto stB2 = [&](int tile, int s) {
#pragma unroll
        for (int h = 0; h < 2; h++) {
            char* d0 = (char*)&sB[s][h][0] + t * 16;
            const unsigned short* s0 = Bb + (ll)(h * 128 + tr) * ldb + tc8 + (ll)tile * 64;
            gll16(s0, d0);
            gll16(s0 + 64 * ldb, d0 + 8192);
        }
    };
    auto ldA4 = [&](int s, bf16x8 (&af)[4][2]) {
        const unsigned short* p0 = &sA[s][wm * 4096];
#pragma unroll
        for (int a2 = 0; a2 < 4; a2++) {
            af[a2][0] = *(const bf16x8*)(p0 + a2 * 1024 + pk0);
            af[a2][1] = *(const bf16x8*)(p0 + a2 * 1024 + pk1);
        }
    };
    auto ldB2 = [&](int s, int g, bf16x8 (&bg)[2][2]) {
        const unsigned short* p0 = &sB[s][wn >> 1][(wn & 1) * 4096 + g * 2048];
#pragma unroll
        for (int b2 = 0; b2 < 2; b2++) {
            bg[b2][0] = *(const bf16x8*)(p0 + b2 * 1024 + pk0);
            bg[b2][1] = *(const bf16x8*)(p0 + b2 * 1024 + pk1);
        }
    };

    f32x4 acc[4][4];
#pragma unroll
    for (int i = 0; i < 4; i++)
#pragma unroll
        for (int j = 0; j < 4; j++) acc[i][j] = (f32x4){0.f, 0.f, 0.f, 0.f};

    bf16x8 af[4][2], bgA[2][2], bgB[2][2];

#define MM128(bg, gn) do { \
    __builtin_amdgcn_s_setprio(1); \
    _Pragma("unroll") \
    for (int a2 = 0; a2 < 4; a2++) \
    _Pragma("unroll") \
    for (int b2 = 0; b2 < 2; b2++) { \
        acc[a2][(gn)*2+b2] = __builtin_amdgcn_mfma_f32_16x16x32_bf16(af[a2][0], bg[b2][0], acc[a2][(gn)*2+b2], 0, 0, 0); \
        acc[a2][(gn)*2+b2] = __builtin_amdgcn_mfma_f32_16x16x32_bf16(af[a2][1], bg[b2][1], acc[a2][(gn)*2+b2], 0, 0, 0); \
    } \
    __builtin_amdgcn_s_setprio(0); \
} while (0)

    // prologue: tiles 0,1 (FIFO: A, B01 per tile)
    stA(0, 0); stB2(0, 0); stA(1, 1); stB2(1, 1);
    VMC(6); BAR;

    const int nT = K >> 6;
    int sl = 0;
    for (int T = 0; T < nT - 2; ++T) {
        const int s2 = (sl >= 1) ? sl - 1 : 2;   // (sl+2)%3
        // q1
        stA(T + 2, s2);
        ldA4(sl, af); ldB2(sl, 0, bgA);
        BAR; LGKM0;
        MM128(bgA, 0);
        BAR;
        // q2
        stB2(T + 2, s2);
        ldB2(sl, 1, bgB);
        BAR; LGKM0;
        MM128(bgB, 1);
        VMC(6);
        BAR;
        sl = (sl >= 2) ? 0 : sl + 1;
    }
    // peel tile nT-2
    {
        ldA4(sl, af); ldB2(sl, 0, bgA);
        BAR; LGKM0;
        MM128(bgA, 0);
        BAR;
        ldB2(sl, 1, bgB);
        BAR; LGKM0;
        MM128(bgB, 1);
        VMC(0);
        BAR;
        sl = (sl >= 2) ? 0 : sl + 1;
    }
    // peel tile nT-1
    {
        ldA4(sl, af); ldB2(sl, 0, bgA);
        LGKM0;
        MM128(bgA, 0);
        ldB2(sl, 1, bgB);
        LGKM0;
        MM128(bgB, 1);
    }

#pragma unroll
    for (int mi = 0; mi < 4; mi++) {
#pragma unroll
        for (int ni = 0; ni < 4; ni++) {
#pragma unroll
            for (int r4 = 0; r4 < 4; r4++) {
                int row = m0 + wm * 64 + mi * 16 + quad * 4 + r4;
                int col = n0 + wn * 64 + ni * 16 + m16;
                ll idx = (ll)row * ldc + col;
                float v = acc[mi][ni][r4] * alpha;
                if (mode == 0) ((float*)C)[idx] = res ? (v + res[idx]) : v;
                else if (mode == 1) ((unsigned short*)C)[idx] = f2bf(v);
                else ((unsigned char*)C)[idx] = (row == col) ? (unsigned char)0 : f2fp8(v);
            }
        }
    }
}

// ============ 8-phase 256x256 fp8 GEMM for the LCA a@G chain ============
// acc = (a*8)[M,K] @ (G*16)[N,K]^T; fused u/c epilogue as before.
__global__ __launch_bounds__(512, 2) void gemm256f8_k(
    const unsigned char* __restrict__ A, ll lda,
    const unsigned char* __restrict__ B, ll ldb,
    int N, int K, float alpha, int mode,
    unsigned short* __restrict__ uu, const unsigned short* __restrict__ cc,
    void* __restrict__ Out)
{
    __shared__ unsigned char sA[2][2][8192];   // [slot][half(128 rows)][128*64B]
    __shared__ unsigned char sB[2][2][8192];

    const int nwg = gridDim.x * gridDim.y;
    int id = blockIdx.y * gridDim.x + blockIdx.x;
    { int q = nwg >> 3, r = nwg & 7, x = id & 7, bb = id >> 3;
      id = (x < r ? x * (q + 1) : r * (q + 1) + (x - r) * q) + bb; }
    const int n0 = (id % gridDim.x) * 256;
    const int m0 = (id / gridDim.x) * 256;

    const unsigned char* Ab = A + (ll)m0 * lda;
    const unsigned char* Bb = B + (ll)n0 * ldb;

    const int t = threadIdx.x;
    const int lane = t & 63;
    const int w = t >> 6, wm = w >> 2, wn = w & 3;
    const int m16 = lane & 15, quad = lane >> 4;

    // stage: region 128 rows x 64B; dst linear t*16; src inverse-swizzled
    const int tr8 = t >> 2;
    const int tc16 = (((t & 3) ^ ((t >> 3) & 3)) << 4);

    // frag read offsets (bytes): chunk (kh*2 + quad>>1) ^ ((m16>>1)&3)
    const int pq0 = m16 * 64 + ((((quad >> 1))     ^ ((m16 >> 1) & 3)) << 4) + ((quad & 1) << 3);
    const int pq1 = m16 * 64 + (((2 + (quad >> 1)) ^ ((m16 >> 1) & 3)) << 4) + ((quad & 1) << 3);

    auto stA = [&](int tile, int h) {
        gll16(Ab + (ll)(h * 128 + tr8) * lda + tc16 + (ll)tile * 64,
              (char*)&sA[tile & 1][h][0] + t * 16);
    };
    auto stB = [&](int tile, int h) {
        gll16(Bb + (ll)(h * 128 + tr8) * ldb + tc16 + (ll)tile * 64,
              (char*)&sB[tile & 1][h][0] + t * 16);
    };
    auto ldA8 = [&](int s, int g, ll (&af)[4][2]) {
        const unsigned char* p0 = &sA[s][wm][g * 4096];
#pragma unroll
        for (int a2 = 0; a2 < 4; a2++) {
            af[a2][0] = *(const ll*)(p0 + a2 * 1024 + pq0);
            af[a2][1] = *(const ll*)(p0 + a2 * 1024 + pq1);
        }
    };
    auto ldB8 = [&](int s, int g, ll (&bg)[2][2]) {
        const unsigned char* p0 = &sB[s][wn >> 1][(wn & 1) * 4096 + g * 2048];
#pragma unroll
        for (int b2 = 0; b2 < 2; b2++) {
            bg[b2][0] = *(const ll*)(p0 + b2 * 1024 + pq0);
            bg[b2][1] = *(const ll*)(p0 + b2 * 1024 + pq1);
        }
    };

    f32x4 acc[8][4];
#pragma unroll
    for (int i = 0; i < 8; i++)
#pragma unroll
        for (int j = 0; j < 4; j++) acc[i][j] = (f32x4){0.f, 0.f, 0.f, 0.f};

    ll afA[4][2], afB[4][2], bgA[2][2], bgB[2][2];

#define MMF8(af, bg, gm, gn) do { \
    __builtin_amdgcn_s_setprio(1); \
    _Pragma("unroll") \
    for (int a2 = 0; a2 < 4; a2++) \
    _Pragma("unroll") \
    for (int b2 = 0; b2 < 2; b2++) { \
        acc[(gm)*4+a2][(gn)*2+b2] = __builtin_amdgcn_mfma_f32_16x16x32_fp8_fp8(af[a2][0], bg[b2][0], acc[(gm)*4+a2][(gn)*2+b2], 0, 0, 0); \
        acc[(gm)*4+a2][(gn)*2+b2] = __builtin_amdgcn_mfma_f32_16x16x32_fp8_fp8(af[a2][1], bg[b2][1], acc[(gm)*4+a2][(gn)*2+b2], 0, 0, 0); \
    } \
    __builtin_amdgcn_s_setprio(0); \
} while (0)

    stB(0, 0); stB(0, 1); stA(0, 0); stA(0, 1); stB(1, 0); stB(1, 1);
    VMC(2); BAR;

#define ITERF8(T, LAST) do { \
    stA((T) + 1, 0); \
    ldA8(0, 0, afA); ldB8(0, 0, bgA); \
    BAR; LGKM0; \
    MMF8(afA, bgA, 0, 0); \
    BAR; \
    stA((T) + 1, 1); \
    ldB8(0, 1, bgB); \
    BAR; LGKM0; \
    MMF8(afA, bgB, 0, 1); \
    BAR; \
    if (!(LAST)) stB((T) + 2, 0); \
    ldA8(0, 1, afB); \
    BAR; LGKM0; \
    MMF8(afB, bgA, 1, 0); \
    BAR; \
    if (!(LAST)) stB((T) + 2, 1); \
    MMF8(afB, bgB, 1, 1); \
    if (LAST) { VMC(0); } else { VMC(2); } \
    BAR; \
    if (!(LAST)) stA((T) + 2, 0); \
    ldA8(1, 0, afA); ldB8(1, 0, bgA); \
    BAR; LGKM0; \
    MMF8(afA, bgA, 0, 0); \
    BAR; \
    if (!(LAST)) stA((T) + 2, 1); \
    ldB8(1, 1, bgB); \
    BAR; LGKM0; \
    MMF8(afA, bgB, 0, 1); \
    BAR; \
    if (!(LAST)) stB((T) + 3, 0); \
    ldA8(1, 1, afB); \
    BAR; LGKM0; \
    MMF8(afB, bgA, 1, 0); \
    BAR; \
    if (!(LAST)) stB((T) + 3, 1); \
    MMF8(afB, bgB, 1, 1); \
    if (!(LAST)) { VMC(2); BAR; } \
} while (0)

    const int nIter = K >> 7;
    for (int i = 0; i < nIter - 1; ++i) ITERF8(2 * i, false);
    ITERF8(2 * (nIter - 1), true);

#pragma unroll
    for (int mi = 0; mi < 8; mi++) {
#pragma unroll
        for (int ni = 0; ni < 4; ni++) {
#pragma unroll
            for (int r = 0; r < 4; r++) {
                int row = m0 + wm * 128 + mi * 16 + quad * 4 + r;
                int col = n0 + wn * 64 + ni * 16 + m16;
                ll idx = (ll)row * N + col;
                float v = acc[mi][ni][r] * alpha;
                float un = 0.9f * bf2f(uu[idx]) + bf2f(cc[idx]) - v;
                uu[idx] = f2bf(un);
                float a = fmaxf(un - 0.1f, 0.0f);
                if (mode == 3) ((unsigned char*)Out)[idx] = f2fp8(a * 8.0f);
                else           ((unsigned short*)Out)[idx] = f2bf(a);
            }
        }
    }
}

// ---------------- generic bf16 MFMA GEMM (scores / PV, z-batched) ----------------
__global__ __launch_bounds__(256) void gemm_bf16(
    const unsigned short* __restrict__ A, ll lda, ll sAz,
    const unsigned short* __restrict__ B, ll ldb, ll sBz,
    void* __restrict__ C, ll ldc, ll sCz,
    int M, int N, int K,
    float alpha, int mode, int causal,
    const float* __restrict__ res)
{
    __shared__ unsigned short sA[2][4096];
    __shared__ unsigned short sB[2][4096];
    const int n0 = blockIdx.x * 128;
    const int m0 = blockIdx.y * 128;
    if (causal && n0 > m0) return;
    const int z = blockIdx.z;

    const unsigned short* Ab = A + (ll)z * sAz + (ll)m0 * lda;
    const unsigned short* Bb = B + (ll)z * sBz + (ll)n0 * ldb;

    const int t    = threadIdx.x;
    const int lane = t & 63;
    const int w    = t >> 6, wm = w >> 1, wn = w & 1;
    const int m16  = lane & 15, quad = lane >> 4;

    const int r0 = t >> 2, cs = t & 3;
    const int r1 = r0 + 64;
    const int c0 = cs ^ ((r0 >> 1) & 3);
    const int c1 = cs ^ ((r1 >> 1) & 3);
    const ll a_off0 = (ll)r0 * lda + c0 * 8;
    const ll a_off1 = (ll)r1 * lda + c1 * 8;
    const ll b_off0 = (ll)r0 * ldb + c0 * 8;
    const ll b_off1 = (ll)r1 * ldb + c1 * 8;
    const int dst = t * 8;

    int aoff[4], boff[4];
#pragma unroll
    for (int mi = 0; mi < 4; mi++) {
        int rr = wm * 64 + mi * 16 + m16;
        aoff[mi] = rr * 32 + ((quad ^ ((rr >> 1) & 3)) << 3);
    }
#pragma unroll
    for (int ni = 0; ni < 4; ni++) {
        int rr = wn * 64 + ni * 16 + m16;
        boff[ni] = rr * 32 + ((quad ^ ((rr >> 1) & 3)) << 3);
    }

    f32x4 acc[4][4];
#pragma unroll
    for (int i = 0; i < 4; i++)
#pragma unroll
        for (int j = 0; j < 4; j++) acc[i][j] = (f32x4){0.f, 0.f, 0.f, 0.f};

    gll16(Ab + a_off0, sA[0] + dst);
    gll16(Ab + a_off1, sA[0] + 2048 + dst);
    gll16(Bb + b_off0, sB[0] + dst);
    gll16(Bb + b_off1, sB[0] + 2048 + dst);
    __syncthreads();

    for (int kt = 0; kt < K; kt += 32) {
        const int cur = (kt >> 5) & 1;
        if (kt + 32 < K) {
            const int nxt = cur ^ 1;
            gll16(Ab + a_off0 + kt + 32, sA[nxt] + dst);
            gll16(Ab + a_off1 + kt + 32, sA[nxt] + 2048 + dst);
            gll16(Bb + b_off0 + kt + 32, sB[nxt] + dst);
            gll16(Bb + b_off1 + kt + 32, sB[nxt] + 2048 + dst);
        }
        bf16x8 af[4], bg[4];
#pragma unroll
        for (int mi = 0; mi < 4; mi++) af[mi] = *(const bf16x8*)(sA[cur] + aoff[mi]);
#pragma unroll
        for (int ni = 0; ni < 4; ni++) bg[ni] = *(const bf16x8*)(sB[cur] + boff[ni]);
#pragma unroll
        for (int mi = 0; mi < 4; mi++)
#pragma unroll
            for (int ni = 0; ni < 4; ni++)
                acc[mi][ni] = __builtin_amdgcn_mfma_f32_16x16x32_bf16(
                    af[mi], bg[ni], acc[mi][ni], 0, 0, 0);
        __syncthreads();
    }

    const ll czoff = (ll)z * sCz;
#pragma unroll
    for (int mi = 0; mi < 4; mi++) {
#pragma unroll
        for (int ni = 0; ni < 4; ni++) {
#pragma unroll
            for (int r = 0; r < 4; r++) {
                int row = m0 + wm * 64 + mi * 16 + quad * 4 + r;
                int col = n0 + wn * 64 + ni * 16 + m16;
                ll idx = czoff + (ll)row * ldc + col;
                float v = acc[mi][ni][r] * alpha;
                if (mode == 0) {
                    ((float*)C)[idx] = res ? (v + res[idx]) : v;
                } else if (mode == 1) {
                    ((unsigned short*)C)[idx] = f2bf(v);
                } else {
                    ((unsigned char*)C)[idx] = (row == col) ? (unsigned char)0 : f2fp8(v);
                }
            }
        }
    }
}

// ---------------- elementwise / transform kernels ----------------

__global__ void wtrans_k(const float* __restrict__ in, unsigned short* __restrict__ out,
                         int R, int C) {
    __shared__ float tile[32][33];
    ll bx = (ll)blockIdx.x * 32, by = (ll)blockIdx.y * 32;
    int tx = threadIdx.x & 31, ty = threadIdx.x >> 5;
#pragma unroll
    for (int i = ty; i < 32; i += 8) tile[i][tx] = in[(by + i) * C + bx + tx];
    __syncthreads();
#pragma unroll
    for (int i = ty; i < 32; i += 8) out[(bx + i) * R + by + tx] = f2bf(tile[tx][i]);
}

__global__ void conv4_k(const float* __restrict__ in, unsigned short* __restrict__ out, ll n) {
    ll i = ((ll)blockIdx.x * 256 + threadIdx.x) * 4;
    if (i >= n) return;
    float4 v = *(const float4*)(in + i);
    out[i] = f2bf(v.x); out[i + 1] = f2bf(v.y); out[i + 2] = f2bf(v.z); out[i + 3] = f2bf(v.w);
}

__global__ void rmsnorm_k(const float* __restrict__ in, const float* __restrict__ w,
                          unsigned short* __restrict__ out) {
    int row = blockIdx.x, t = threadIdx.x;
    const float* x = in + (ll)row * 2048;
    float v[8]; float s = 0.f;
#pragma unroll
    for (int i = 0; i < 8; i++) { v[i] = x[t + i * 256]; s += v[i] * v[i]; }
#pragma unroll
    for (int o = 32; o > 0; o >>= 1) s += __shfl_xor(s, o, 64);
    __shared__ float rs[4];
    if ((t & 63) == 0) rs[t >> 6] = s;
    __syncthreads();
    s = (rs[0] + rs[1] + rs[2] + rs[3]) * (1.0f / 2048.0f);
    float sc = rsqrtf(s + 1e-6f);
    unsigned short* o_ = out + (ll)row * 2048;
#pragma unroll
    for (int i = 0; i < 8; i++) o_[t + i * 256] = f2bf(v[i] * sc * w[t + i * 256]);
}

// in-place RoPE on fused qkv [4096 rows][6144] (q at 0, k at +2048)
__global__ void rope_k(unsigned short* __restrict__ qkv) {
    int idx = blockIdx.x * 256 + threadIdx.x;
    int j = idx & 63;
    int h = (idx >> 6) & 15;
    int row = idx >> 10;
    int s = row & 2047;
    float f = __expf(-(float)j * 0.14391156831212783f);
    float ang = (float)s * f;
    float sn, cs;
    sincosf(ang, &sn, &cs);
    ll base = (ll)row * 6144 + h * 128 + j;
    float x1 = bf2f(qkv[base]), x2 = bf2f(qkv[base + 64]);
    qkv[base]      = f2bf(x1 * cs - x2 * sn);
    qkv[base + 64] = f2bf(x2 * cs + x1 * sn);
    x1 = bf2f(qkv[base + 2048]); x2 = bf2f(qkv[base + 2112]);
    qkv[base + 2048] = f2bf(x1 * cs - x2 * sn);
    qkv[base + 2112] = f2bf(x2 * cs + x1 * sn);
}

// V region of qkv [4096,(h,128)] (stride 6144, offset 4096) -> VT [b,h][128][2048]
__global__ void vtrans_k(const unsigned short* __restrict__ qkv, unsigned short* __restrict__ out) {
    __shared__ unsigned short tile[32][33];
    int z = blockIdx.z, b = z >> 4, h = z & 15;
    const unsigned short* ib = qkv + (ll)b * 2048 * 6144 + 4096 + h * 128;
    unsigned short* ob = out + (ll)z * 262144;
    int bx = blockIdx.x * 32, by = blockIdx.y * 32;
    int tx = threadIdx.x & 31, ty = threadIdx.x >> 5;
#pragma unroll
    for (int i = ty; i < 32; i += 8) tile[i][tx] = ib[(ll)(by + i) * 6144 + bx + tx];
    __syncthreads();
#pragma unroll
    for (int i = ty; i < 32; i += 8) ob[(ll)(bx + i) * 2048 + by + tx] = tile[tx][i];
}

__global__ void softmax_k(unsigned short* __restrict__ sc) {
    int q = blockIdx.x, z = blockIdx.y, t = threadIdx.x;
    unsigned short* row = sc + (ll)z * 4194304 + (ll)q * 2048;
    float x[8]; float m = -1e30f;
#pragma unroll
    for (int i = 0; i < 8; i++) {
        int kk = t + i * 256;
        x[i] = (kk <= q) ? bf2f(row[kk]) : -1e30f;
        m = fmaxf(m, x[i]);
    }
#pragma unroll
    for (int o = 32; o > 0; o >>= 1) m = fmaxf(m, __shfl_xor(m, o, 64));
    __shared__ float rm[4];
    if ((t & 63) == 0) rm[t >> 6] = m;
    __syncthreads();
    m = fmaxf(fmaxf(rm[0], rm[1]), fmaxf(rm[2], rm[3]));
    float s = 0.f;
#pragma unroll
    for (int i = 0; i < 8; i++) {
        int kk = t + i * 256;
        float e = (kk <= q) ? __expf(x[i] - m) : 0.0f;
        x[i] = e; s += e;
    }
#pragma unroll
    for (int o = 32; o > 0; o >>= 1) s += __shfl_xor(s, o, 64);
    __shared__ float rsum[4];
    if ((t & 63) == 0) rsum[t >> 6] = s;
    __syncthreads();
    s = rsum[0] + rsum[1] + rsum[2] + rsum[3];
    float inv = 1.0f / s;
#pragma unroll
    for (int i = 0; i < 8; i++) row[t + i * 256] = f2bf(x[i] * inv);
}

__global__ void lca_init_k(const unsigned short* __restrict__ c, unsigned short* __restrict__ u,
                           unsigned char* __restrict__ a) {
    ll i = ((ll)blockIdx.x * 256 + threadIdx.x) * 4;
#pragma unroll
    for (int j = 0; j < 4; j++) {
        unsigned short cv = c[i + j];
        u[i + j] = cv;
        a[i + j] = f2fp8(fmaxf(bf2f(cv) - 0.1f, 0.f) * 8.0f);
    }
}

// gu layout [4096][16384]: gate cols 0..8191, up cols 8192..16383
__global__ void swiglu_k(unsigned short* __restrict__ gu) {
    ll i = ((ll)blockIdx.x * 256 + threadIdx.x) * 4;
    ll row = i >> 13, col = i & 8191;
    unsigned short* g = gu + row * 16384 + col;
    const unsigned short* u = g + 8192;
#pragma unroll
    for (int j = 0; j < 4; j++) {
        float x = bf2f(g[j]);
        float y = bf2f(u[j]);
        g[j] = f2bf(x / (1.0f + __expf(-x)) * y);
    }
}

// ---------------- host orchestration ----------------
extern "C" void kernel_launch(void* const* d_in, const int* in_sizes, int n_in,
                              void* d_out, int out_size, void* d_ws, size_t ws_size,
                              hipStream_t stream) {
    (void)in_sizes; (void)n_in; (void)out_size; (void)ws_size;
    const float* X        = (const float*)d_in[0];
    const float* wln_in   = (const float*)d_in[1];
    const float* wln_lca  = (const float*)d_in[2];
    const float* wln_post = (const float*)d_in[3];
    const float* Wq   = (const float*)d_in[4];
    const float* Wk   = (const float*)d_in[5];
    const float* Wv   = (const float*)d_in[6];
    const float* Wo   = (const float*)d_in[7];
    const float* Wlca = (const float*)d_in[8];
    const float* Wg   = (const float*)d_in[9];
    const float* Wu   = (const float*)d_in[10];
    const float* Wd   = (const float*)d_in[11];
    float* out = (float*)d_out;

    char* ws = (char*)d_ws;
    unsigned short* WqT = (unsigned short*)(ws);          // [6144][2048] fused qkv weights
    unsigned short* WkT = WqT + 4194304;
    unsigned short* WvT = WqT + 2 * 4194304;
    unsigned short* WoT = WqT + 3 * 4194304;
    unsigned short* WgT = WqT;                             // MLP reuse: [16384][2048] fused
    unsigned short* WlcaT = (unsigned short*)(ws + 33554432);
    unsigned short* Wlcab = WlcaT + 8388608;
    unsigned short* WuT   = WlcaT;
    unsigned short* h_bf = (unsigned short*)(ws + 67108864);
    char* pool = ws + 83886080;
    // attention phase
    unsigned short* qkv    = (unsigned short*)(pool);               // [4096][6144] bf16 (48MB)
    unsigned short* VT     = (unsigned short*)(pool + 50331648);
    unsigned short* attn   = (unsigned short*)(pool + 67108864);
    unsigned short* scores = (unsigned short*)(pool + 83886080);
    float* h1              = (float*)(pool + 150994944);
    // LCA phase
    unsigned short* cbuf   = (unsigned short*)(pool);
    unsigned short* ubuf   = (unsigned short*)(pool + 33554432);
    unsigned char* a8_0    = (unsigned char*)(pool + 67108864);
    unsigned char* a8_1    = (unsigned char*)(pool + 83886080);
    unsigned short* abf    = (unsigned short*)(pool + 100663296);
    unsigned char* Gf8     = (unsigned char*)(pool + 134217728);
    float* h2              = (float*)(pool + 150994944);
    // MLP phase
    unsigned short* gu     = (unsigned short*)(pool);               // [4096][16384] (128MB)
    unsigned short* WdT    = (unsigned short*)(pool + 201326592);

    dim3 blk(256);
    auto gemm = [&](const unsigned short* A, ll lda, ll sAz,
                    const unsigned short* Bt, ll ldb, ll sBz,
                    void* C, ll ldc, ll sCz,
                    int M, int N, int K, int Z,
                    float alpha, int mode, int causal, const float* res) {
        dim3 g(N / 128, M / 128, Z);
        gemm_bf16<<<g, blk, 0, stream>>>(A, lda, sAz, Bt, ldb, sBz, C, ldc, sCz,
                                         M, N, K, alpha, mode, causal, res);
    };
    auto g256 = [&](const unsigned short* A, ll lda, const unsigned short* Bt, ll ldb,
                    void* C, ll ldc, int M, int N, int K, float alpha, int mode,
                    const float* res) {
        dim3 g(N / 256, M / 256);
        gemm256_k<<<g, dim3(512), 0, stream>>>(A, lda, Bt, ldb, C, ldc, K, alpha, mode, res);
    };
    auto g128 = [&](const unsigned short* A, ll lda, const unsigned short* Bt, ll ldb,
                    void* C, ll ldc, int M, int N, int K, float alpha, int mode,
                    const float* res) {
        dim3 g(N / 256, M / 128);
        gemm128_k<<<g, dim3(512), 0, stream>>>(A, lda, Bt, ldb, C, ldc, K, alpha, mode, res);
    };

    // --- weight prep ---
    wtrans_k<<<dim3(64, 64), blk, 0, stream>>>(Wq, WqT, 2048, 2048);
    wtrans_k<<<dim3(64, 64), blk, 0, stream>>>(Wk, WkT, 2048, 2048);
    wtrans_k<<<dim3(64, 64), blk, 0, stream>>>(Wv, WvT, 2048, 2048);
    wtrans_k<<<dim3(64, 64), blk, 0, stream>>>(Wo, WoT, 2048, 2048);
    wtrans_k<<<dim3(128, 64), blk, 0, stream>>>(Wlca, WlcaT, 2048, 4096);
    conv4_k<<<8192, blk, 0, stream>>>(Wlca, Wlcab, 8388608LL);

    // --- attention ---
    rmsnorm_k<<<4096, blk, 0, stream>>>(X, wln_in, h_bf);
    // fused QKV: [4096,2048] @ [6144,2048]^T -> [4096][6144]
    g256(h_bf, 2048, WqT, 2048, qkv, 6144, 4096, 6144, 2048, 1.f, 1, nullptr);
    rope_k<<<16384, blk, 0, stream>>>(qkv);
    vtrans_k<<<dim3(4, 64, 32), blk, 0, stream>>>(qkv, VT);
    for (int c = 0; c < 4; c++) {
        int b = c >> 1, h0 = (c & 1) * 8;
        const unsigned short* qbase = qkv + (ll)b * 2048 * 6144 + h0 * 128;
        const unsigned short* kbase = qbase + 2048;
        gemm(qbase, 6144, 128, kbase, 6144, 128, scores, 2048, 4194304LL,
             2048, 2048, 128, 8, 0.08838834764831845f, 1, 1, nullptr);
        softmax_k<<<dim3(2048, 8), blk, 0, stream>>>(scores);
        const unsigned short* vtb = VT + (ll)(b * 16 + h0) * 262144;
        unsigned short* ab = attn + (ll)b * 4194304 + h0 * 128;
        gemm(scores, 2048, 4194304LL, vtb, 2048, 262144LL, ab, 2048, 128,
             2048, 128, 2048, 8, 1.f, 1, 0, nullptr);
    }
    g128(attn, 2048, WoT, 2048, h1, 2048, 4096, 2048, 2048, 1.f, 0, X);

    // --- LCA ---
    rmsnorm_k<<<4096, blk, 0, stream>>>(h1, wln_lca, h_bf);
    g256(WlcaT, 2048, WlcaT, 2048, Gf8, 4096, 4096, 4096, 2048, 16.f, 2, nullptr);
    g256(h_bf, 2048, WlcaT, 2048, cbuf, 4096, 4096, 4096, 2048, 0.1f, 1, nullptr);
    lca_init_k<<<16384, blk, 0, stream>>>(cbuf, ubuf, a8_0);
    unsigned char* acur = a8_0; unsigned char* anext = a8_1;
    for (int i = 0; i < 9; i++) {
        int mode = (i < 8) ? 3 : 4;
        void* outp = (i < 8) ? (void*)anext : (void*)abf;
        gemm256f8_k<<<dim3(16, 16), dim3(512), 0, stream>>>(
            acur, 4096, Gf8, 4096, 4096, 4096,
            0.1f / 128.0f, mode, ubuf, cbuf, outp);
        unsigned char* tmp = acur; acur = anext; anext = tmp;
    }
    g128(abf, 4096, Wlcab, 4096, h2, 2048, 4096, 2048, 4096, 1.f, 0, nullptr);

    // --- MLP ---
    wtrans_k<<<dim3(256, 64), blk, 0, stream>>>(Wg, WgT, 2048, 8192);
    wtrans_k<<<dim3(256, 64), blk, 0, stream>>>(Wu, WuT, 2048, 8192);
    wtrans_k<<<dim3(64, 256), blk, 0, stream>>>(Wd, WdT, 8192, 2048);
    rmsnorm_k<<<4096, blk, 0, stream>>>(h2, wln_post, h_bf);
    // fused gate|up: [4096,2048] @ [16384,2048]^T -> gu [4096][16384]
    g256(h_bf, 2048, WgT, 2048, gu, 16384, 4096, 16384, 2048, 1.f, 1, nullptr);
    swiglu_k<<<32768, blk, 0, stream>>>(gu);
    g128(gu, 16384, WdT, 8192, out, 2048, 4096, 2048, 8192, 1.f, 0, h2);
}